// Round 2
// baseline (115.862 us; speedup 1.0000x reference)
//
#include <hip/hip_runtime.h>
#include <stdint.h>

#define T1c 128
#define T2c 512
#define TPc 8
#define Cc  129
#define Dc  256

// ---- workspace layout (float-unit offsets) ----
// mf:    [0,      65536)   mask as float, [t1][t2]
// pp:    [65536,  69632)   packed pos (int), [p][t2]
// Apart: [69632,  73728)   [t1][q=4][p=8]  partial sum m*base^2
// c64p:  [73728,  74240)   [t1][q=4]       partial sum m*(dsum/8-vv)^2
// mbase: [74240, 598528)   [t1][p][t2]     m*base
#define WS_MF  0
#define WS_PP  65536
#define WS_AP  69632
#define WS_C64 73728
#define WS_MB  74240

__device__ __forceinline__ int pack_loc(int v) {
    int a = v < 0 ? -v : v;
    return a | (v < 0 ? (int)0x80000000 : 0);
}

// packed v1 ^ packed v2: bit31 = sign product, low bits = |c1|^|c2|
__device__ __forceinline__ void dist_core(unsigned v1, unsigned v2, float& dd, float& val) {
    unsigned xv = v1 ^ v2;
    unsigned xr = xv & 0x7FFFFFFFu;
    // e = bitlen(xr+1) = 32-clz;  1 - e/16 = clz/16 - 1
    val = fmaf((float)__clz((int)(xr + 1u)), 0.0625f, -1.0f);
    dd  = __uint_as_float(__float_as_uint(val) ^ (xv & 0x80000000u));
}

__device__ __forceinline__ float wave_sum(float v) {
    #pragma unroll
    for (int off = 32; off; off >>= 1) v += __shfl_xor(v, off, 64);
    return v;
}

// K1: grid (t1=128 x quarter=4) = 512 blocks, 256 threads (4 waves).
// Per block: val_v for a 128-wide t2 slice (wave-per-t2 dot, fused row norms),
// mask decode -> mf, pack pos -> pp (t1==0 blocks), mbase, A partials, c64 partials.
__global__ __launch_bounds__(256, 2) void k_prep(
    const float* __restrict__ e1, const float* __restrict__ e2,
    const int* __restrict__ sta, const int* __restrict__ pos,
    const void* __restrict__ mask, float* __restrict__ ws) {
    int b = blockIdx.x;
    int t1 = b >> 2, q = b & 3;
    int tid = threadIdx.x;
    int lane = tid & 63, w = tid >> 6;

    __shared__ float svv[128];
    __shared__ float smf[128];
    __shared__ float swA[2][9];
    __shared__ int sflag;

    // mask format: 4-byte elems (int32/fp32 of 0/1) have zero bytes at offset 1 mod 4;
    // 1-byte bool has ~80% nonzero there.
    if (tid == 0) sflag = 0;
    __syncthreads();
    if (((const unsigned char*)mask)[1 + 4 * tid] != 0) atomicOr(&sflag, 1);
    __syncthreads();

    // e1 row fragment stays in registers; inverse norm via butterfly (all lanes get it)
    float4 a4 = ((const float4*)(e1 + (size_t)t1 * Dc))[lane];
    float inv1 = rsqrtf(wave_sum(a4.x * a4.x + a4.y * a4.y + a4.z * a4.z + a4.w * a4.w));

    // wave-per-t2: 128 t2 / 4 waves = 32 rounds
    for (int r = 0; r < 32; ++r) {
        int t2i = q * 128 + r * 4 + w;
        float4 x = ((const float4*)(e2 + (size_t)t2i * Dc))[lane];
        float dot = a4.x * x.x + a4.y * x.y + a4.z * x.z + a4.w * x.w;
        float ss  = x.x * x.x + x.y * x.y + x.z * x.z + x.w * x.w;
        dot = wave_sum(dot);
        ss  = wave_sum(ss);
        if (lane == 0) {
            float vv = dot * inv1 * rsqrtf(ss);
            int idx = t1 * T2c + t2i;
            float m;
            if (sflag) m = (((const unsigned char*)mask)[idx] != 0) ? 1.0f : 0.0f;
            else       m = (((const int*)mask)[idx] != 0) ? 1.0f : 0.0f;
            svv[t2i & 127] = vv;
            smf[t2i & 127] = m;
            ws[WS_MF + idx] = m;
        }
    }
    __syncthreads();

    if (tid < 128) {
        int t2 = q * 128 + tid;
        float vv = svv[tid];
        float m  = smf[tid];
        int4 pr0 = ((const int4*)(pos + (size_t)t2 * TPc))[0];
        int4 pr1 = ((const int4*)(pos + (size_t)t2 * TPc))[1];
        int pk[8] = {pack_loc(pr0.x), pack_loc(pr0.y), pack_loc(pr0.z), pack_loc(pr0.w),
                     pack_loc(pr1.x), pack_loc(pr1.y), pack_loc(pr1.z), pack_loc(pr1.w)};
        int4 s0 = ((const int4*)(sta + (size_t)t1 * TPc))[0];
        int4 s1 = ((const int4*)(sta + (size_t)t1 * TPc))[1];
        int sk[8] = {pack_loc(s0.x), pack_loc(s0.y), pack_loc(s0.z), pack_loc(s0.w),
                     pack_loc(s1.x), pack_loc(s1.y), pack_loc(s1.z), pack_loc(s1.w)};
        float d[8];
        float dsum = 0.f;
        #pragma unroll
        for (int p = 0; p < 8; ++p) {
            float dd, val;
            dist_core((unsigned)sk[p], (unsigned)pk[p], dd, val);
            d[p] = dd;
            dsum += dd;
        }
        float acc[9];
        #pragma unroll
        for (int p = 0; p < 8; ++p) {
            float mb = m * ((dsum - d[p]) * 0.125f - vv);
            ws[WS_MB + ((size_t)t1 * TPc + p) * T2c + t2] = mb;
            acc[p] = mb * mb;
        }
        float c6 = dsum * 0.125f - vv;
        acc[8] = m * c6 * c6;
        #pragma unroll
        for (int j = 0; j < 9; ++j) acc[j] = wave_sum(acc[j]);
        if (lane == 0) {
            #pragma unroll
            for (int j = 0; j < 9; ++j) swA[w][j] = acc[j];
        }
        if (t1 == 0) {
            int* wspp = (int*)(ws + WS_PP);
            #pragma unroll
            for (int p = 0; p < 8; ++p) wspp[p * T2c + t2] = pk[p];
        }
    }
    __syncthreads();
    if (tid < 8)   ws[WS_AP + ((size_t)t1 * 4 + q) * 8 + tid] = swA[0][tid] + swA[1][tid];
    if (tid == 8)  ws[WS_C64 + (size_t)t1 * 4 + q] = swA[0][8] + swA[1][8];
}

// K2: grid (t1=128 x cg=2) = 256 blocks, 256 threads: thread = (c = cg*32 + tid>>3, p = tid&7).
// Full 512-deep t2 loop per thread -> direct stores, no atomics, no memset.
// loss[c] = A + B/4 + Q/64, loss[65+c] = A - B/4 + Q/64 (== loss[c] if res==0), loss[64] from partials.
__global__ __launch_bounds__(256, 1) void k_main(
    const int* __restrict__ sta, const int* __restrict__ rm,
    const float* __restrict__ ws, float* __restrict__ out) {
    int b = blockIdx.x;
    int t1 = b >> 1, cg = b & 1;
    int tid = threadIdx.x;
    int p = tid & 7;
    int c = cg * 32 + (tid >> 3);     // [0, 64)
    int i = c >> 2, k = c & 3;
    int stav = sta[t1 * TPc + p];
    int low  = rm[(((t1 * 16 + i) * 4 + k) * TPc) + p] & ((1 << i) - 1);
    int resv = (stav ^ (1 << i)) ^ low;
    unsigned v1 = (unsigned)pack_loc(resv);

    const int4*   pp4 = (const int4*)((const int*)(ws + WS_PP) + p * T2c);
    const float4* mb4 = (const float4*)(ws + WS_MB + ((size_t)t1 * TPc + p) * T2c);
    const float4* mf4 = (const float4*)(ws + WS_MF + (size_t)t1 * T2c);

    float B = 0.f, Q = 0.f;
    #pragma unroll 4
    for (int j = 0; j < 128; ++j) {
        int4   pv = pp4[j];
        float4 mb = mb4[j];
        float4 mm = mf4[j];
        float dd, val;
        dist_core(v1, (unsigned)pv.x, dd, val);
        B = fmaf(mb.x, dd, B); Q = fmaf(mm.x * dd, dd, Q);
        dist_core(v1, (unsigned)pv.y, dd, val);
        B = fmaf(mb.y, dd, B); Q = fmaf(mm.y * dd, dd, Q);
        dist_core(v1, (unsigned)pv.z, dd, val);
        B = fmaf(mb.z, dd, B); Q = fmaf(mm.z * dd, dd, Q);
        dist_core(v1, (unsigned)pv.w, dd, val);
        B = fmaf(mb.w, dd, B); Q = fmaf(mm.w * dd, dd, Q);
    }
    const float* Ap = ws + WS_AP + (size_t)t1 * 32;
    float A = (Ap[0 * 8 + p] + Ap[1 * 8 + p]) + (Ap[2 * 8 + p] + Ap[3 * 8 + p]);
    float core = A + Q * (1.0f / 64.0f);
    float l0 = core + B * 0.25f;
    float l1 = (resv == 0) ? l0 : core - B * 0.25f;
    out[((size_t)t1 * Cc + c) * TPc + p] = l0;
    out[((size_t)t1 * Cc + 65 + c) * TPc + p] = l1;
    if (cg == 0 && tid < 8) {
        const float* cp = ws + WS_C64 + (size_t)t1 * 4;
        out[((size_t)t1 * Cc + 64) * TPc + tid] = (cp[0] + cp[1]) + (cp[2] + cp[3]);
    }
}

extern "C" void kernel_launch(void* const* d_in, const int* in_sizes, int n_in,
                              void* d_out, int out_size, void* d_ws, size_t ws_size,
                              hipStream_t stream) {
    const float* emb1 = (const float*)d_in[0];
    const float* emb2 = (const float*)d_in[1];
    const int*   sta  = (const int*)d_in[2];
    const int*   pos  = (const int*)d_in[3];
    const void*  mask = d_in[4];
    const int*   rm   = (const int*)d_in[5];
    float* ws = (float*)d_ws;

    hipLaunchKernelGGL(k_prep, dim3(512), dim3(256), 0, stream,
                       emb1, emb2, sta, pos, mask, ws);
    hipLaunchKernelGGL(k_main, dim3(256), dim3(256), 0, stream,
                       sta, rm, ws, (float*)d_out);
}

// Round 3
// 84.317 us; speedup vs baseline: 1.3741x; 1.3741x over previous
//
#include <hip/hip_runtime.h>
#include <stdint.h>

#define T1c 128
#define T2c 512
#define TPc 8
#define Cc  129
#define Dc  256
#define T2H 256          // t2 half processed per block
#define MBS 260          // padded LDS row stride: banks (260*p+4j)%32 = (4p+4j)%32 -> conflict-free b128

__device__ __forceinline__ int pack_loc(int v) {
    int a = v < 0 ? -v : v;
    return a | (v < 0 ? (int)0x80000000 : 0);
}

// packed v1 ^ packed v2: bit31 = sign product, low bits = |c1|^|c2|
// val = clz(xr+1)/16 - 1  (== 1 - bitlen/16);  dd = val with sign-product applied
__device__ __forceinline__ void dist_core(unsigned v1, unsigned v2, float& dd, float& val) {
    unsigned xv = v1 ^ v2;
    unsigned xr = xv & 0x7FFFFFFFu;
    val = fmaf((float)__clz((int)(xr + 1u)), 0.0625f, -1.0f);
    dd  = __uint_as_float(__float_as_uint(val) ^ (xv & 0x80000000u));
}

__device__ __forceinline__ float wave_sum(float v) {
    #pragma unroll
    for (int off = 32; off; off >>= 1) v += __shfl_xor(v, off, 64);
    return v;
}

// One fused kernel. grid = 256 blocks (t1 x t2-half), block = 512 threads (8 waves).
// Phase 0: mask-format flag + e1 row -> LDS + inv-norm.
// Phase 1: val_v dots, 2 threads per t2 (d split), serial per-thread accumulation (no shuffles).
// Phase 2: pack pos, dis_sta, mbase/mf -> LDS; block-reduce A[p] and the c=64 row partial.
// Phase 3: thread=(c,p): B = sum mb*d, Q = sum m*val^2 from LDS; loss via mirror identity:
//   loss[c] = A + B/4 + Q/64 ; loss[65+c] = A - B/4 + Q/64 (== loss[c] if res==0); atomicAdd halves.
__global__ __launch_bounds__(512) void k_fused(
    const float* __restrict__ e1, const float* __restrict__ e2,
    const int* __restrict__ sta, const int* __restrict__ pos,
    const void* __restrict__ mask, const int* __restrict__ rm,
    float* __restrict__ out) {
    int b  = blockIdx.x;
    int t1 = b >> 1;
    int th = b & 1;
    int base = th * T2H;
    int tid  = threadIdx.x;
    int lane = tid & 63, wv = tid >> 6;

    __shared__ float se1[Dc];
    __shared__ float smb[TPc][MBS];
    __shared__ int   spp[TPc][MBS];
    __shared__ float smf[T2H];
    __shared__ float sred[4][9];
    __shared__ float sA[9];
    __shared__ float sdot[512], sss[512];
    __shared__ float sinv1;
    __shared__ int   sflag;

    // ---- phase 0 ----
    if (tid == 0) sflag = 0;
    __syncthreads();
    if (((const unsigned char*)mask)[1 + 4 * tid] != 0) atomicOr(&sflag, 1);
    if (wv == 0) {
        float4 a = ((const float4*)(e1 + (size_t)t1 * Dc))[lane];
        ((float4*)se1)[lane] = a;
        float s = wave_sum(a.x * a.x + a.y * a.y + a.z * a.z + a.w * a.w);
        if (lane == 0) sinv1 = rsqrtf(s);
    }
    __syncthreads();

    // ---- phase 1: dot + sumsq, 2 threads per t2 (halves of D) ----
    {
        int t2l = tid >> 1, h = tid & 1;
        int t2  = base + t2l;
        const float4* xrow = (const float4*)(e2 + (size_t)t2 * Dc) + h * 32;
        const float4* arow = (const float4*)se1 + h * 32;
        float dot = 0.f, ss = 0.f;
        #pragma unroll 8
        for (int d = 0; d < 32; ++d) {
            float4 x = xrow[d];
            float4 a = arow[d];
            dot = fmaf(a.x, x.x, fmaf(a.y, x.y, fmaf(a.z, x.z, fmaf(a.w, x.w, dot))));
            ss  = fmaf(x.x, x.x, fmaf(x.y, x.y, fmaf(x.z, x.z, fmaf(x.w, x.w, ss))));
        }
        sdot[tid] = dot;
        sss[tid]  = ss;
    }
    __syncthreads();

    // ---- phase 2: mbase / pp / mf into LDS, A + c64 partials ----
    if (tid < T2H) {
        int t2 = base + tid;
        float dot = sdot[2 * tid] + sdot[2 * tid + 1];
        float ss  = sss[2 * tid]  + sss[2 * tid + 1];
        float vv  = dot * sinv1 * rsqrtf(ss);
        int idx = t1 * T2c + t2;
        float m;
        if (sflag) m = (((const unsigned char*)mask)[idx] != 0) ? 1.0f : 0.0f;
        else       m = (((const int*)mask)[idx] != 0) ? 1.0f : 0.0f;
        smf[tid] = m;

        int4 p0 = ((const int4*)(pos + (size_t)t2 * TPc))[0];
        int4 p1 = ((const int4*)(pos + (size_t)t2 * TPc))[1];
        int pk[8] = {pack_loc(p0.x), pack_loc(p0.y), pack_loc(p0.z), pack_loc(p0.w),
                     pack_loc(p1.x), pack_loc(p1.y), pack_loc(p1.z), pack_loc(p1.w)};
        int4 s0 = ((const int4*)(sta + (size_t)t1 * TPc))[0];
        int4 s1 = ((const int4*)(sta + (size_t)t1 * TPc))[1];
        int sk[8] = {pack_loc(s0.x), pack_loc(s0.y), pack_loc(s0.z), pack_loc(s0.w),
                     pack_loc(s1.x), pack_loc(s1.y), pack_loc(s1.z), pack_loc(s1.w)};
        float d[8];
        float dsum = 0.f;
        #pragma unroll
        for (int p = 0; p < 8; ++p) {
            float dd, val;
            dist_core((unsigned)sk[p], (unsigned)pk[p], dd, val);
            d[p] = dd;
            dsum += dd;
        }
        float acc[9];
        #pragma unroll
        for (int p = 0; p < 8; ++p) {
            float mb = m * ((dsum - d[p]) * 0.125f - vv);
            smb[p][tid] = mb;
            spp[p][tid] = pk[p];
            acc[p] = mb * mb;
        }
        float c6 = dsum * 0.125f - vv;
        acc[8] = m * c6 * c6;
        #pragma unroll
        for (int j = 0; j < 9; ++j) acc[j] = wave_sum(acc[j]);
        if (lane == 0) {
            #pragma unroll
            for (int j = 0; j < 9; ++j) sred[wv][j] = acc[j];
        }
    }
    __syncthreads();
    if (tid < 9) {
        float v = (sred[0][tid] + sred[1][tid]) + (sred[2][tid] + sred[3][tid]);
        sA[tid] = v;
    }
    __syncthreads();

    // ---- phase 3: c-loop from LDS ----
    int p = tid & 7;
    int c = tid >> 3;                 // [0, 64)
    int i = c >> 2, kk = c & 3;
    int stav = sta[t1 * TPc + p];
    int low  = rm[(((t1 * 16 + i) * 4 + kk) * TPc) + p] & ((1 << i) - 1);
    int resv = (stav ^ (1 << i)) ^ low;
    unsigned v1 = (unsigned)pack_loc(resv);

    const int4*   pp4 = (const int4*)&spp[p][0];
    const float4* mb4 = (const float4*)&smb[p][0];
    const float4* mf4 = (const float4*)smf;

    float B = 0.f, Q = 0.f;
    #pragma unroll 4
    for (int j = 0; j < 64; ++j) {
        int4   pv = pp4[j];
        float4 mb = mb4[j];
        float4 mm = mf4[j];
        float dd, val;
        dist_core(v1, (unsigned)pv.x, dd, val);
        B = fmaf(mb.x, dd, B); Q = fmaf(mm.x * val, val, Q);
        dist_core(v1, (unsigned)pv.y, dd, val);
        B = fmaf(mb.y, dd, B); Q = fmaf(mm.y * val, val, Q);
        dist_core(v1, (unsigned)pv.z, dd, val);
        B = fmaf(mb.z, dd, B); Q = fmaf(mm.z * val, val, Q);
        dist_core(v1, (unsigned)pv.w, dd, val);
        B = fmaf(mb.w, dd, B); Q = fmaf(mm.w * val, val, Q);
    }
    float A = sA[p];
    float core = fmaf(Q, 1.0f / 64.0f, A);
    float l0 = fmaf(B,  0.25f, core);
    float l1 = (resv == 0) ? l0 : fmaf(B, -0.25f, core);
    atomicAdd(&out[((size_t)t1 * Cc + c) * TPc + p], l0);
    atomicAdd(&out[((size_t)t1 * Cc + 65 + c) * TPc + p], l1);
    if (tid < 8) atomicAdd(&out[((size_t)t1 * Cc + 64) * TPc + tid], sA[8]);
}

extern "C" void kernel_launch(void* const* d_in, const int* in_sizes, int n_in,
                              void* d_out, int out_size, void* d_ws, size_t ws_size,
                              hipStream_t stream) {
    const float* emb1 = (const float*)d_in[0];
    const float* emb2 = (const float*)d_in[1];
    const int*   sta  = (const int*)d_in[2];
    const int*   pos  = (const int*)d_in[3];
    const void*  mask = d_in[4];
    const int*   rm   = (const int*)d_in[5];

    hipMemsetAsync(d_out, 0, (size_t)T1c * Cc * TPc * sizeof(float), stream);
    hipLaunchKernelGGL(k_fused, dim3(256), dim3(512), 0, stream,
                       emb1, emb2, sta, pos, mask, rm, (float*)d_out);
}